// Round 14
// baseline (446.584 us; speedup 1.0000x reference)
//
#include <hip/hip_runtime.h>
#include <math.h>

#define NB 8
#define NL 2048
#define ND 1024
#define NH 16
#define KTOP 7

typedef __attribute__((ext_vector_type(4))) float f32x4;
typedef __attribute__((ext_vector_type(8))) short s16x8;
typedef __attribute__((ext_vector_type(8))) _Float16 f16x8;
typedef __attribute__((ext_vector_type(4))) _Float16 f16x4;

__device__ __forceinline__ unsigned short f2bf(float x) {
  unsigned u = __float_as_uint(x);
  u = (u + 0x7FFFu + ((u >> 16) & 1u)) >> 16;
  return (unsigned short)u;
}
__device__ __forceinline__ float bf2f(unsigned short h) {
  return __uint_as_float(((unsigned)h) << 16);
}
__device__ __forceinline__ unsigned cvtpk_bf16(float a, float b) {
  unsigned d;
  asm("v_cvt_pk_bf16_f32 %0, %1, %2" : "=v"(d) : "v"(a), "v"(b));
  return d;  // [15:0]=bf16(a), [31:16]=bf16(b), RNE
}
__device__ __forceinline__ float lo16(unsigned h) { return __uint_as_float(h << 16); }
__device__ __forceinline__ float hi16(unsigned h) { return __uint_as_float(h & 0xffff0000u); }

__device__ __forceinline__ void gll16(const void* g, void* l) {
  __builtin_amdgcn_global_load_lds(
      (const __attribute__((address_space(1))) void*)g,
      (__attribute__((address_space(3))) void*)l, 16, 0, 0);
}

// split f32x8 -> bf16 hi/lo uint4 pair, store to LDS
__device__ __forceinline__ void asplit_write(float4 x, float4 y, short* ah, short* al, int wi) {
  unsigned h0 = cvtpk_bf16(x.x, x.y);
  unsigned h1 = cvtpk_bf16(x.z, x.w);
  unsigned h2 = cvtpk_bf16(y.x, y.y);
  unsigned h3 = cvtpk_bf16(y.z, y.w);
  float r0 = x.x - lo16(h0), r1 = x.y - hi16(h0);
  float r2 = x.z - lo16(h1), r3 = x.w - hi16(h1);
  float r4 = y.x - lo16(h2), r5 = y.y - hi16(h2);
  float r6 = y.z - lo16(h3), r7 = y.w - hi16(h3);
  unsigned l0 = cvtpk_bf16(r0, r1);
  unsigned l1 = cvtpk_bf16(r2, r3);
  unsigned l2 = cvtpk_bf16(r4, r5);
  unsigned l3 = cvtpk_bf16(r6, r7);
  *(uint4*)(ah + wi) = make_uint4(h0, h1, h2, h3);
  *(uint4*)(al + wi) = make_uint4(l0, l1, l2, l3);
}

// ---------------- weight prep ----------------
// y=0,1 (wq,wk): transpose -> split bf16 hi/lo, swizzled for BK=32 (k ^ (((n>>1)&3)<<3))
// y=2,3 (wv,wo): transpose -> f16, swizzled for BK=64 tiles (k ^ ((n&7)<<3))
__global__ __launch_bounds__(256) void wprep_kernel(
    const float* __restrict__ w0, const float* __restrict__ w1,
    const float* __restrict__ w2, const float* __restrict__ w3,
    short* __restrict__ wsplit, _Float16* __restrict__ wf16) {
  __shared__ float tile[32][33];
  int y = blockIdx.y;
  const float* in = (y == 0) ? w0 : (y == 1) ? w1 : (y == 2) ? w2 : w3;
  int bx = blockIdx.x & 31, by = blockIdx.x >> 5;
  int tx = threadIdx.x & 31, ty = threadIdx.x >> 5;
#pragma unroll
  for (int i = 0; i < 4; ++i)
    tile[ty + i * 8][tx] = in[(size_t)(by * 32 + ty + i * 8) * ND + bx * 32 + tx];
  __syncthreads();
#pragma unroll
  for (int i = 0; i < 4; ++i) {
    float x = tile[tx][ty + i * 8];
    int n = bx * 32 + ty + i * 8;
    int k = by * 32 + tx;
    if (y < 2) {
      short* oh = wsplit + (size_t)(2 * y) * ND * ND;
      short* ol = wsplit + (size_t)(2 * y + 1) * ND * ND;
      unsigned short h = f2bf(x);
      unsigned short l = f2bf(x - bf2f(h));
      size_t o = (size_t)n * ND + (k ^ (((n >> 1) & 3) << 3));
      oh[o] = (short)h;
      ol[o] = (short)l;
    } else {
      _Float16* of = wf16 + (size_t)(y - 2) * ND * ND;
      of[(size_t)n * ND + (k ^ ((n & 7) << 3))] = (_Float16)x;
    }
  }
}

// ---------------- split-bf16 GEMM: C^T = (A f32 x BT split-bf16), out (B,1024,2048) f32 -----
// FUSED Q+K: 2048 blocks; sel = wg>>10 picks {queries,wq,Qt} vs {keys,wk,Kt}.
// Double-buffered BK=32: issue-early staging (A global->reg, B gll->LDS), write-late A split.
__global__ __launch_bounds__(256) void gemm_split(
    const float* __restrict__ Aq, const float* __restrict__ Ak,
    const short* __restrict__ wsplit, float* __restrict__ Qt, float* __restrict__ Kt) {
  constexpr int K = 1024;
  // 64KB: buf b at b*16384 shorts; within buf: ah 0, al 4096, bh 8192, bl 12288
  __shared__ short smem[32768];
  int t = threadIdx.x;
  // bijective XCD swizzle over 2048 blocks; each XCD stays within one operand set
  int wg = (blockIdx.x & 7) * 256 + (blockIdx.x >> 3);
  int sel = wg >> 10;
  int wgl = wg & 1023;
  const float* A = sel ? Ak : Aq;
  const short* BhT = wsplit + (size_t)(sel ? 2 : 0) * ND * ND;
  const short* BlT = wsplit + (size_t)(sel ? 3 : 1) * ND * ND;
  float* Ct = sel ? Kt : Qt;
  int m0 = (wgl >> 3) << 7, n0 = (wgl & 7) << 7;
  int lane = t & 63;
  int wm = (t >> 7) & 1, wn = (t >> 6) & 1;
  int lrow = lane & 15, lk8 = (lane >> 4) << 3;

  // staging geometry (per thread): rows r0 (it=0) and r1=r0+64 (it=1), k-chunk c8
  int r0 = t >> 2, r1 = r0 + 64;
  int c8 = (t & 3) << 3;
  int wi0 = r0 * 32 + (c8 ^ (((r0 >> 1) & 3) << 3));
  int wi1 = r1 * 32 + (c8 ^ (((r1 >> 1) & 3) << 3));
  int lo0 = (t & 192) * 8;         // wave-uniform LDS offset (shorts), it=0
  int lo1 = 2048 + (t & 192) * 8;  // it=1

  const float* pa0 = A + (size_t)(m0 + r0) * K + c8;
  const float* pa1 = A + (size_t)(m0 + r1) * K + c8;
  const short* pb0h = BhT + (size_t)(n0 + r0) * K + c8;
  const short* pb1h = BhT + (size_t)(n0 + r1) * K + c8;
  const short* pb0l = BlT + (size_t)(n0 + r0) * K + c8;
  const short* pb1l = BlT + (size_t)(n0 + r1) * K + c8;

  // loop-invariant fragment read offsets (shorts within a buffer)
  int iA[4], iB[4];
#pragma unroll
  for (int f = 0; f < 4; ++f) {
    int ra = wm * 64 + f * 16 + lrow;
    iA[f] = ra * 32 + (lk8 ^ (((ra >> 1) & 3) << 3));
    int rb = wn * 64 + f * 16 + lrow;
    iB[f] = rb * 32 + (lk8 ^ (((rb >> 1) & 3) << 3));
  }

  f32x4 acc[4][4] = {};

  // ---- prologue: stage k0=0 into buf0 ----
  float4 sx0 = *(const float4*)(pa0);
  float4 sy0 = *(const float4*)(pa0 + 4);
  float4 sx1 = *(const float4*)(pa1);
  float4 sy1 = *(const float4*)(pa1 + 4);
  gll16(pb0h, smem + 8192 + lo0);
  gll16(pb1h, smem + 8192 + lo1);
  gll16(pb0l, smem + 12288 + lo0);
  gll16(pb1l, smem + 12288 + lo1);
  asplit_write(sx0, sy0, smem, smem + 4096, wi0);
  asplit_write(sx1, sy1, smem, smem + 4096, wi1);
  __syncthreads();

  for (int k0 = 0; k0 < K; k0 += 32) {
    short* cb = smem + ((k0 >> 5) & 1) * 16384;
    short* nb = smem + ((((k0 >> 5) & 1) ^ 1) * 16384);
    bool more = (k0 + 32) < K;
    if (more) {
      // issue-early: next A tile -> regs, next B tile -> LDS (async)
      sx0 = *(const float4*)(pa0 + k0 + 32);
      sy0 = *(const float4*)(pa0 + k0 + 36);
      sx1 = *(const float4*)(pa1 + k0 + 32);
      sy1 = *(const float4*)(pa1 + k0 + 36);
      gll16(pb0h + k0 + 32, nb + 8192 + lo0);
      gll16(pb1h + k0 + 32, nb + 8192 + lo1);
      gll16(pb0l + k0 + 32, nb + 12288 + lo0);
      gll16(pb1l + k0 + 32, nb + 12288 + lo1);
    }
    // ---- compute from cb ----
    s16x8 afh[4], afl[4];
#pragma unroll
    for (int mf = 0; mf < 4; ++mf) {
      afh[mf] = *(const s16x8*)(cb + iA[mf]);
      afl[mf] = *(const s16x8*)(cb + 4096 + iA[mf]);
    }
#pragma unroll
    for (int nf = 0; nf < 4; ++nf) {
      s16x8 bfh = *(const s16x8*)(cb + 8192 + iB[nf]);
      s16x8 bfl = *(const s16x8*)(cb + 12288 + iB[nf]);
      // term-grouped: same-acc dependency distance = 4 MFMAs
#pragma unroll
      for (int mf = 0; mf < 4; ++mf)
        acc[mf][nf] = __builtin_amdgcn_mfma_f32_16x16x32_bf16(afh[mf], bfh, acc[mf][nf], 0, 0, 0);
#pragma unroll
      for (int mf = 0; mf < 4; ++mf)
        acc[mf][nf] = __builtin_amdgcn_mfma_f32_16x16x32_bf16(afh[mf], bfl, acc[mf][nf], 0, 0, 0);
#pragma unroll
      for (int mf = 0; mf < 4; ++mf)
        acc[mf][nf] = __builtin_amdgcn_mfma_f32_16x16x32_bf16(afl[mf], bfh, acc[mf][nf], 0, 0, 0);
    }
    if (more) {
      // write-late: split A into nb (compiler waits only the A loads, gll stays in flight)
      asplit_write(sx0, sy0, nb, nb + 4096, wi0);
      asplit_write(sx1, sy1, nb, nb + 4096, wi1);
    }
    __syncthreads();
  }

  // epilogue: C^T (B,1024,2048) f32, float4 stores along m
  int b = m0 >> 11;
  int mlbase = (m0 & 2047) + wm * 64 + (lane >> 4) * 4;
#pragma unroll
  for (int nf = 0; nf < 4; ++nf) {
    int n = n0 + wn * 64 + nf * 16 + lrow;
    float* rowp = Ct + ((size_t)(b * ND + n)) * NL + mlbase;
#pragma unroll
    for (int mf = 0; mf < 4; ++mf)
      *(float4*)(rowp + mf * 16) = *(float4*)&acc[mf][nf];
  }
}

// ---------------- f16 GEMM: A x BT(f16 pre-swizzled, gll), double-buffered ----------------
// AF32: A is f32 natural (issue-early reg stage, write-late cvt); else A f16 pre-swizzled (gll).
// OUTMODE 0: C^T (B,1024,2048) f16.
// OUTMODE 1: fused roll epilogue -> Xs (B*NL rows, swizzled f16).  Block owns 2 full heads.
// OUTMODE 2: C natural (16384x1024) f32.
template <int OUTMODE, bool AF32>
__global__ __launch_bounds__(256) void gemm_f16(
    const void* __restrict__ Av, const _Float16* __restrict__ BT,
    void* __restrict__ Cv, const float* __restrict__ topw, const int* __restrict__ topi) {
  constexpr int K = 1024;
  // 64KB: buf b at b*16384 halfs; within buf: sA 0, sB 8192. Reused as f32[128][128] in OUTMODE 1.
  __shared__ _Float16 smem[32768];
  __shared__ float wls[128][KTOP];
  __shared__ int tls[128][KTOP];
  int t = threadIdx.x;
  int wg = (blockIdx.x & 7) * 128 + (blockIdx.x >> 3);
  int m0 = (wg >> 3) << 7, n0 = (wg & 7) << 7;
  int lane = t & 63;
  int wm = (t >> 7) & 1, wn = (t >> 6) & 1;
  int lrow = lane & 15, lk = (lane >> 4) << 3;

  // staging geometry: per it (0..3): row = it*32 + (t>>3), k-chunk c8 = (t&7)*8
  int rs = t >> 3;
  int c8 = (t & 7) << 3;
  const _Float16* pB[4];
  const float* pAf[4];
  const _Float16* pAh[4];
  int wiA[4], lo[4];
#pragma unroll
  for (int it = 0; it < 4; ++it) {
    int r = it * 32 + rs;
    pB[it] = BT + (size_t)(n0 + r) * K + c8;
    lo[it] = it * 2048 + (t & 192) * 8;
    if (AF32) {
      pAf[it] = (const float*)Av + (size_t)(m0 + r) * K + c8;
      wiA[it] = r * 64 + (c8 ^ ((r & 7) << 3));
    } else {
      pAh[it] = (const _Float16*)Av + (size_t)(m0 + r) * K + c8;
    }
  }

  f32x4 acc[4][4] = {};
  float4 ax[4], ay[4];

  // prologue: stage k0=0 into buf0
#pragma unroll
  for (int it = 0; it < 4; ++it) {
    gll16(pB[it], smem + 8192 + lo[it]);
    if (!AF32) {
      gll16(pAh[it], smem + lo[it]);
    } else {
      ax[it] = *(const float4*)(pAf[it]);
      ay[it] = *(const float4*)(pAf[it] + 4);
    }
  }
  if (AF32) {
#pragma unroll
    for (int it = 0; it < 4; ++it) {
      f16x8 o;
      o[0] = (_Float16)ax[it].x; o[1] = (_Float16)ax[it].y;
      o[2] = (_Float16)ax[it].z; o[3] = (_Float16)ax[it].w;
      o[4] = (_Float16)ay[it].x; o[5] = (_Float16)ay[it].y;
      o[6] = (_Float16)ay[it].z; o[7] = (_Float16)ay[it].w;
      *(f16x8*)(smem + wiA[it]) = o;
    }
  }
  __syncthreads();

  for (int k0 = 0; k0 < K; k0 += 64) {
    _Float16* cb = smem + ((k0 >> 6) & 1) * 16384;
    _Float16* nb = smem + ((((k0 >> 6) & 1) ^ 1) * 16384);
    bool more = (k0 + 64) < K;
    if (more) {
#pragma unroll
      for (int it = 0; it < 4; ++it) {
        gll16(pB[it] + k0 + 64, nb + 8192 + lo[it]);
        if (!AF32) {
          gll16(pAh[it] + k0 + 64, nb + lo[it]);
        } else {
          ax[it] = *(const float4*)(pAf[it] + k0 + 64);
          ay[it] = *(const float4*)(pAf[it] + k0 + 68);
        }
      }
    }
    // compute from cb
#pragma unroll
    for (int kk = 0; kk < 64; kk += 32) {
      f16x8 af[4];
#pragma unroll
      for (int mf = 0; mf < 4; ++mf) {
        int row = wm * 64 + mf * 16 + lrow;
        af[mf] = *(const f16x8*)(cb + row * 64 + ((kk + lk) ^ ((row & 7) << 3)));
      }
#pragma unroll
      for (int nf = 0; nf < 4; ++nf) {
        int row = wn * 64 + nf * 16 + lrow;
        f16x8 bf = *(const f16x8*)(cb + 8192 + row * 64 + ((kk + lk) ^ ((row & 7) << 3)));
#pragma unroll
        for (int mf = 0; mf < 4; ++mf)
          acc[mf][nf] = __builtin_amdgcn_mfma_f32_16x16x32_f16(af[mf], bf, acc[mf][nf], 0, 0, 0);
      }
    }
    if (more && AF32) {
#pragma unroll
      for (int it = 0; it < 4; ++it) {
        f16x8 o;
        o[0] = (_Float16)ax[it].x; o[1] = (_Float16)ax[it].y;
        o[2] = (_Float16)ax[it].z; o[3] = (_Float16)ax[it].w;
        o[4] = (_Float16)ay[it].x; o[5] = (_Float16)ay[it].y;
        o[6] = (_Float16)ay[it].z; o[7] = (_Float16)ay[it].w;
        *(f16x8*)(nb + wiA[it]) = o;
      }
    }
    __syncthreads();
  }

  if (OUTMODE == 0) {
    _Float16* C = (_Float16*)Cv;
    int b = m0 >> 11;
    int ml = (m0 & 2047) + wm * 64 + (lane >> 4) * 4;
#pragma unroll
    for (int nf = 0; nf < 4; ++nf) {
      int n = n0 + wn * 64 + nf * 16 + lrow;
      _Float16* row = C + ((size_t)(b * ND + n)) * NL + ml;
#pragma unroll
      for (int mf = 0; mf < 4; ++mf) {
        f16x4 v;
        v[0] = (_Float16)acc[mf][nf][0];
        v[1] = (_Float16)acc[mf][nf][1];
        v[2] = (_Float16)acc[mf][nf][2];
        v[3] = (_Float16)acc[mf][nf][3];
        *(f16x4*)(row + mf * 16) = v;
      }
    }
  } else if (OUTMODE == 1) {
    // --- fused roll (mod-64 over Dh) + weight + scramble, from f32 acc ---
    float* ct = (float*)smem;  // 64KB (last __syncthreads of main loop protects reuse)
#pragma unroll
    for (int nf = 0; nf < 4; ++nf) {
      int nl = wn * 64 + nf * 16 + lrow;
#pragma unroll
      for (int mf = 0; mf < 4; ++mf) {
        int ml = wm * 64 + (lane >> 4) * 4 + mf * 16;
        int cc = (((ml >> 2) ^ (nl & 7)) << 2);
        *(float4*)(ct + nl * 128 + cc) = *(float4*)&acc[mf][nf];
      }
    }
    int b = m0 >> 11;
    int h0 = n0 >> 6;  // first head of the block (even)
    for (int e = t; e < 128 * KTOP; e += 256) {
      int nl = e / KTOP, i = e - nl * KTOP;  // nl = h_loc*64 + d
      size_t rix = ((size_t)(b * 16 + h0 + (nl >> 6))) * 64 + (nl & 63);
      wls[nl][i] = topw[rix * KTOP + i];
      tls[nl][i] = topi[rix * KTOP + i] & 63;
    }
    __syncthreads();

    int hi = (m0 >> 10) & 1;
    int cbase = (m0 & 2047) & 1023;  // D-col base (block spans 128 cols, hi fixed)
    _Float16* O = (_Float16*)Cv;
#pragma unroll
    for (int it2 = 0; it2 < 16; ++it2) {
      int o = it2 * 1024 + t * 4;
      int lr = o >> 7;    // local row = d*2 + h_loc
      int c4 = o & 127;   // m_local, multiple of 4
      int d = lr >> 1, hl = lr & 1;
      int wrow = hl * 64 + d;
      float4 s = {0.f, 0.f, 0.f, 0.f};
#pragma unroll
      for (int i = 0; i < KTOP; ++i) {
        int sr = hl * 64 + ((d - tls[wrow][i]) & 63);
        float w = wls[wrow][i];
        int scc = (((c4 >> 2) ^ (sr & 7)) << 2);
        float4 v = *(const float4*)(ct + sr * 128 + scc);
        s.x += w * v.x; s.y += w * v.y; s.z += w * v.z; s.w += w * v.w;
      }
      int rowp = d * 32 + (h0 + hl) * 2 + hi;
      int cg = cbase + c4;
      int cs = cg ^ ((rowp & 7) << 3);  // swizzle for O-GEMM's gll consumer
      f16x4 v4;
      v4[0] = (_Float16)s.x; v4[1] = (_Float16)s.y;
      v4[2] = (_Float16)s.z; v4[3] = (_Float16)s.w;
      *(f16x4*)(O + ((size_t)(b * NL + rowp)) * ND + cs) = v4;
    }
  } else {
    float* C = (float*)Cv;
#pragma unroll
    for (int mf = 0; mf < 4; ++mf)
#pragma unroll
      for (int nf = 0; nf < 4; ++nf) {
        int row = m0 + wm * 64 + mf * 16 + (lane >> 4) * 4;
        int col = n0 + wn * 64 + nf * 16 + lrow;
#pragma unroll
        for (int r = 0; r < 4; ++r)
          C[(size_t)(row + r) * ND + col] = acc[mf][nf][r];
      }
  }
}

// =================== FFT correlation + top-7 + softmax (register Stockham) ===================
__device__ __forceinline__ int SW(int i) { return i ^ ((i >> 4) & 7); }

__device__ __forceinline__ float2 cadd2(float2 a, float2 b) { return make_float2(a.x + b.x, a.y + b.y); }
__device__ __forceinline__ float2 csub2(float2 a, float2 b) { return make_float2(a.x - b.x, a.y - b.y); }
__device__ __forceinline__ float2 cmul2(float2 a, float2 b) {
  return make_float2(a.x * b.x - a.y * b.y, a.x * b.y + a.y * b.x);
}
__device__ __forceinline__ float2 cjs2(float2 a, float s) { return make_float2(-s * a.y, s * a.x); }
// e^{i*2*pi*rev} via HW trig (input in revolutions, |rev| < 1)
__device__ __forceinline__ float2 wtw(float rev) {
  return make_float2(__builtin_amdgcn_cosf(rev), __builtin_amdgcn_sinf(rev));
}

__device__ __forceinline__ void dft4(float2& b0, float2& b1, float2& b2, float2& b3, float s) {
  float2 t0 = cadd2(b0, b2), t1 = csub2(b0, b2);
  float2 t2 = cadd2(b1, b3), t3 = cjs2(csub2(b1, b3), s);
  b0 = cadd2(t0, t2);
  b1 = cadd2(t1, t3);
  b2 = csub2(t0, t2);
  b3 = csub2(t1, t3);
}

__device__ __forceinline__ void dft8(float2 a[8], float s) {
  float2 e0 = a[0], e1 = a[2], e2 = a[4], e3 = a[6];
  float2 o0 = a[1], o1 = a[3], o2 = a[5], o3 = a[7];
  dft4(e0, e1, e2, e3, s);
  dft4(o0, o1, o2, o3, s);
  const float c = 0.70710678118654752f;
  float2 w1 = make_float2(c, s * c);
  float2 w3 = make_float2(-c, s * c);
  o1 = cmul2(o1, w1);
  o2 = cjs2(o2, s);
  o3 = cmul2(o3, w3);
  a[0] = cadd2(e0, o0);
  a[4] = csub2(e0, o0);
  a[1] = cadd2(e1, o1);
  a[5] = csub2(e1, o1);
  a[2] = cadd2(e2, o2);
  a[6] = csub2(e2, o2);
  a[3] = cadd2(e3, o3);
  a[7] = csub2(e3, o3);
}

template <int LS>
__device__ __forceinline__ void pass8(const float2* __restrict__ in, float2* __restrict__ out,
                                      float s, int t) {
  float2 a[8];
  const float2* ip = in + (t ^ ((t >> 4) & 7));  // SW(t+256r) = SW(t)+256r (256r in bits>=8)
#pragma unroll
  for (int r = 0; r < 8; ++r) a[r] = ip[256 * r];
  int k = t & (LS - 1);
  if (LS > 1) {
    float kf = s * (1.0f / (LS * 8)) * (float)k;
    float2 w1 = wtw(kf);
    float2 w4 = wtw(4.0f * kf);
    float2 w2 = cmul2(w1, w1);
    float2 w3 = cmul2(w2, w1);
    float2 w5 = cmul2(w4, w1);
    float2 w6 = cmul2(w4, w2);
    float2 w7 = cmul2(w4, w3);
    a[1] = cmul2(a[1], w1);
    a[2] = cmul2(a[2], w2);
    a[3] = cmul2(a[3], w3);
    a[4] = cmul2(a[4], w4);
    a[5] = cmul2(a[5], w5);
    a[6] = cmul2(a[6], w6);
    a[7] = cmul2(a[7], w7);
  }
  dft8(a, s);
  int ob = (t / LS) * (LS * 8) + k;
#pragma unroll
  for (int r = 0; r < 8; ++r) out[SW(ob + LS * r)] = a[r];
}

__global__ __launch_bounds__(256) void fft_topk_kernel(
    const float* __restrict__ Qt, const float* __restrict__ Kt,
    float* __restrict__ topw, int* __restrict__ topi) {
  // LDS exactly 32KB -> 5 blocks/CU. cwv/cwt alias into X (X is dead by then).
  __shared__ float2 X[2048];
  __shared__ float2 Y[2048];
  float* cwv = (float*)X;         // 32 floats
  int* cwt = ((int*)X) + 32;      // 32 ints (256B total, within X)

  int t = threadIdx.x;
  size_t rix = blockIdx.x;
  const float* q = Qt + rix * NL;
  const float* k = Kt + rix * NL;

  // load packed z = Q + i*K. SW(i0+j) = SW(i0) ^ j for j<4 (XOR, not add!)
#pragma unroll
  for (int it = 0; it < 2; ++it) {
    int i0 = 4 * t + 1024 * it;
    float4 vq = *(const float4*)(q + i0);
    float4 vk = *(const float4*)(k + i0);
    int swb = SW(i0);
    X[swb ^ 0] = make_float2(vq.x, vk.x);
    X[swb ^ 1] = make_float2(vq.y, vk.y);
    X[swb ^ 2] = make_float2(vq.z, vk.z);
    X[swb ^ 3] = make_float2(vq.w, vk.w);
  }
  __syncthreads();

  // forward FFT (sign = -1): radix 8,8,8,4
  pass8<1>(X, Y, -1.0f, t);
  __syncthreads();
  pass8<8>(Y, X, -1.0f, t);
  __syncthreads();
  pass8<64>(X, Y, -1.0f, t);
  __syncthreads();

  // forward dft4 pass (Y -> X), keeping own outputs in fz[8] (zf re-reads avoided)
  float2 fz[8];
#pragma unroll
  for (int h = 0; h < 2; ++h) {
    int b = t + 256 * h;
    float2 a[4];
    const float2* yp = Y + SW(b);  // SW(b+512r)=SW(b)+512r (512r in bits>=9)
#pragma unroll
    for (int r = 0; r < 4; ++r) a[r] = yp[512 * r];
    float2 w = wtw(-(1.0f / 2048.0f) * (float)b);
    float2 w2 = cmul2(w, w);
    a[1] = cmul2(a[1], w);
    a[2] = cmul2(a[2], w2);
    a[3] = cmul2(a[3], cmul2(w2, w));
    dft4(a[0], a[1], a[2], a[3], -1.0f);
    float2* xp = X + SW(b);
#pragma unroll
    for (int r = 0; r < 4; ++r) {
      xp[512 * r] = a[r];
      fz[h + 2 * r] = a[r];
    }
  }
  __syncthreads();

  // FUSED: spectrum untangle (S = FQ*conj(FK) / 2048) + first inverse radix-8 pass -> Y.
  {
    float2 a[8];
#pragma unroll
    for (int r = 0; r < 8; ++r) {
      int f = t + 256 * r;
      int nf = (2048 - f) & 2047;
      float2 zf = fz[r];
      float2 zn = X[SW(nf)];
      float aa = zf.x, b2 = zf.y, c = zn.x, d = zn.y;
      float p = 0.5f * (aa + c), qq = 0.5f * (b2 - d);
      float r2 = 0.5f * (b2 + d), s2 = -0.5f * (aa - c);
      a[r] = make_float2((p * r2 + qq * s2) * (1.0f / 2048.0f),
                         (qq * r2 - p * s2) * (1.0f / 2048.0f));
    }
    dft8(a, 1.0f);  // LS=1: no twiddles
    int ob = t * 8;
#pragma unroll
    for (int r = 0; r < 8; ++r) Y[SW(ob + r)] = a[r];
  }
  __syncthreads();

  // remaining inverse passes: 8, 64, then final radix-4 kept in registers (reads Y)
  pass8<8>(Y, X, 1.0f, t);
  __syncthreads();
  pass8<64>(X, Y, 1.0f, t);
  __syncthreads();

  float lv[8];
  int lt[8];
#pragma unroll
  for (int h = 0; h < 2; ++h) {
    int b = t + 256 * h;
    float2 a[4];
    const float2* yp = Y + SW(b);
#pragma unroll
    for (int r = 0; r < 4; ++r) a[r] = yp[512 * r];
    float2 w = wtw((1.0f / 2048.0f) * (float)b);
    float2 w2 = cmul2(w, w);
    a[1] = cmul2(a[1], w);
    a[2] = cmul2(a[2], w2);
    a[3] = cmul2(a[3], cmul2(w2, w));
    dft4(a[0], a[1], a[2], a[3], 1.0f);
#pragma unroll
    for (int r = 0; r < 4; ++r) {
      lv[h * 4 + r] = a[r].x;
      lt[h * 4 + r] = b + 512 * r;
    }
  }

  // ---- top-7, barrier-light: wave-local 7 passes (no barriers), 1 barrier, wave-0 merge ----
  // X is dead now; cwv/cwt alias into it (the __syncthreads below orders the reuse).
  int lane = t & 63, wave = t >> 6;
  float bv = lv[0];
  int bt = lt[0];
#pragma unroll
  for (int j = 1; j < 8; ++j)
    if (lv[j] > bv) { bv = lv[j]; bt = lt[j]; }

  float myv = 0.f;
  int myt = 0;
#pragma unroll
  for (int pass = 0; pass < KTOP; ++pass) {
    float rv = bv;
    int rt = bt;
#pragma unroll
    for (int m = 1; m < 64; m <<= 1) {
      float ov = __shfl_xor(rv, m, 64);
      int ot = __shfl_xor(rt, m, 64);
      if (ov > rv) { rv = ov; rt = ot; }
    }
    if (lane == pass) { myv = rv; myt = rt; }  // static capture (lane==pass)
    if (bt == rt) {  // owner lane: invalidate + rescan (wave-local, position-unique)
#pragma unroll
      for (int j = 0; j < 8; ++j)
        if (lt[j] == rt) lv[j] = -3.0e38f;
      bv = lv[0];
      bt = lt[0];
#pragma unroll
      for (int j = 1; j < 8; ++j)
        if (lv[j] > bv) { bv = lv[j]; bt = lt[j]; }
    }
  }
  __syncthreads();  // all waves done reading X/Y before cwv/cwt overwrite X
  if (lane < KTOP) {
    cwv[wave * 8 + lane] = myv;
    cwt[wave * 8 + lane] = myt;
  }
  __syncthreads();

  if (wave == 0) {
    float mv = -3.0e38f;
    int mt = 0x7FFFFFFF;
    if (lane < 32 && (lane & 7) < KTOP) {
      mv = cwv[lane];
      mt = cwt[lane];
    }
    float sv = 0.f;
    int st = 0;
#pragma unroll
    for (int pass = 0; pass < KTOP; ++pass) {
      float rv = mv;
      int rt = mt;
#pragma unroll
      for (int m = 1; m < 64; m <<= 1) {
        float ov = __shfl_xor(rv, m, 64);
        int ot = __shfl_xor(rt, m, 64);
        if (ov > rv) { rv = ov; rt = ot; }
      }
      if (lane == pass) { sv = rv; st = rt; }
      if (mt == rt) mv = -3.0e38f;  // invalidate own candidate (tau unique)
    }
    // softmax over the 7 selected (lanes 0..6 hold sv/st)
    float m0v = __shfl(sv, 0, 64);
    float e = (lane < KTOP) ? expf(sv - m0v) : 0.0f;
    float ssum = e;
#pragma unroll
    for (int m = 1; m < 64; m <<= 1) ssum += __shfl_xor(ssum, m, 64);
    if (lane < KTOP) {
      topw[rix * KTOP + lane] = e / ssum;
      topi[rix * KTOP + lane] = st;
    }
  }
}

// ------------------------------------- launcher ---------------------------------------------
extern "C" void kernel_launch(void* const* d_in, const int* in_sizes, int n_in,
                              void* d_out, int out_size, void* d_ws, size_t ws_size,
                              hipStream_t stream) {
  (void)in_sizes; (void)n_in; (void)out_size; (void)ws_size;
  const float* queries = (const float*)d_in[0];
  const float* keys    = (const float*)d_in[1];
  const float* values  = (const float*)d_in[2];
  const float* wq = (const float*)d_in[3];
  const float* wk = (const float*)d_in[4];
  const float* wv = (const float*)d_in[5];
  const float* wo = (const float*)d_in[6];
  float* outp = (float*)d_out;

  const size_t MB = 1024 * 1024;
  char* ws = (char*)d_ws;
  short*    wsplit = (short*)ws;                  // wq/wk bf16 hi+lo: 8MB
  _Float16* wf16   = (_Float16*)(ws + 8 * MB);    // wv,wo f16: 4MB
  float*    Qt     = (float*)(ws + 12 * MB);      // (8,1024,2048) f32 = 64MB
  float*    Kt     = (float*)(ws + 76 * MB);      // 64MB; later Xs (f16)
  float*    topw   = (float*)(ws + 140 * MB);
  int*      topi   = (int*)(ws + 140 * MB + (size_t)8192 * KTOP * 4);

  _Float16* wv16 = wf16 + (size_t)0 * ND * ND;
  _Float16* wo16 = wf16 + (size_t)1 * ND * ND;

  _Float16* Xs = (_Float16*)Kt;  // reuse after fft

  wprep_kernel<<<dim3(1024, 4), 256, 0, stream>>>(wq, wk, wv, wo, wsplit, wf16);

  // fused Q+K projections (2048 blocks; sel by wg>>10)
  gemm_split<<<2048, 256, 0, stream>>>(queries, keys, wsplit, Qt, Kt);

  fft_topk_kernel<<<8192, 256, 0, stream>>>(Qt, Kt, topw, topi);

  // V projection + fused roll + scramble -> Xs (Kt dead after fft)
  gemm_f16<1, true><<<1024, 256, 0, stream>>>(values, wv16, Xs, topw, topi);

  gemm_f16<2, false><<<1024, 256, 0, stream>>>(Xs, wo16, outp, nullptr, nullptr);
}

// Round 15
// 441.126 us; speedup vs baseline: 1.0124x; 1.0124x over previous
//
#include <hip/hip_runtime.h>
#include <math.h>

#define NB 8
#define NL 2048
#define ND 1024
#define NH 16
#define KTOP 7

typedef __attribute__((ext_vector_type(4))) float f32x4;
typedef __attribute__((ext_vector_type(8))) short s16x8;
typedef __attribute__((ext_vector_type(8))) _Float16 f16x8;
typedef __attribute__((ext_vector_type(4))) _Float16 f16x4;

__device__ __forceinline__ unsigned short f2bf(float x) {
  unsigned u = __float_as_uint(x);
  u = (u + 0x7FFFu + ((u >> 16) & 1u)) >> 16;
  return (unsigned short)u;
}
__device__ __forceinline__ float bf2f(unsigned short h) {
  return __uint_as_float(((unsigned)h) << 16);
}
__device__ __forceinline__ unsigned cvtpk_bf16(float a, float b) {
  unsigned d;
  asm("v_cvt_pk_bf16_f32 %0, %1, %2" : "=v"(d) : "v"(a), "v"(b));
  return d;  // [15:0]=bf16(a), [31:16]=bf16(b), RNE
}
__device__ __forceinline__ float lo16(unsigned h) { return __uint_as_float(h << 16); }
__device__ __forceinline__ float hi16(unsigned h) { return __uint_as_float(h & 0xffff0000u); }

__device__ __forceinline__ void gll16(const void* g, void* l) {
  __builtin_amdgcn_global_load_lds(
      (const __attribute__((address_space(1))) void*)g,
      (__attribute__((address_space(3))) void*)l, 16, 0, 0);
}

// split f32x8 -> bf16 hi/lo uint4 pair, store to LDS
__device__ __forceinline__ void asplit_write(float4 x, float4 y, short* ah, short* al, int wi) {
  unsigned h0 = cvtpk_bf16(x.x, x.y);
  unsigned h1 = cvtpk_bf16(x.z, x.w);
  unsigned h2 = cvtpk_bf16(y.x, y.y);
  unsigned h3 = cvtpk_bf16(y.z, y.w);
  float r0 = x.x - lo16(h0), r1 = x.y - hi16(h0);
  float r2 = x.z - lo16(h1), r3 = x.w - hi16(h1);
  float r4 = y.x - lo16(h2), r5 = y.y - hi16(h2);
  float r6 = y.z - lo16(h3), r7 = y.w - hi16(h3);
  unsigned l0 = cvtpk_bf16(r0, r1);
  unsigned l1 = cvtpk_bf16(r2, r3);
  unsigned l2 = cvtpk_bf16(r4, r5);
  unsigned l3 = cvtpk_bf16(r6, r7);
  *(uint4*)(ah + wi) = make_uint4(h0, h1, h2, h3);
  *(uint4*)(al + wi) = make_uint4(l0, l1, l2, l3);
}

// ---------------- weight prep ----------------
// y=0,1 (wq,wk): transpose -> split bf16 hi/lo, swizzled for BK=32 (k ^ (((n>>1)&3)<<3))
// y=2,3 (wv,wo): transpose -> f16, swizzled for BK=64 tiles (k ^ ((n&7)<<3))
__global__ __launch_bounds__(256) void wprep_kernel(
    const float* __restrict__ w0, const float* __restrict__ w1,
    const float* __restrict__ w2, const float* __restrict__ w3,
    short* __restrict__ wsplit, _Float16* __restrict__ wf16) {
  __shared__ float tile[32][33];
  int y = blockIdx.y;
  const float* in = (y == 0) ? w0 : (y == 1) ? w1 : (y == 2) ? w2 : w3;
  int bx = blockIdx.x & 31, by = blockIdx.x >> 5;
  int tx = threadIdx.x & 31, ty = threadIdx.x >> 5;
#pragma unroll
  for (int i = 0; i < 4; ++i)
    tile[ty + i * 8][tx] = in[(size_t)(by * 32 + ty + i * 8) * ND + bx * 32 + tx];
  __syncthreads();
#pragma unroll
  for (int i = 0; i < 4; ++i) {
    float x = tile[tx][ty + i * 8];
    int n = bx * 32 + ty + i * 8;
    int k = by * 32 + tx;
    if (y < 2) {
      short* oh = wsplit + (size_t)(2 * y) * ND * ND;
      short* ol = wsplit + (size_t)(2 * y + 1) * ND * ND;
      unsigned short h = f2bf(x);
      unsigned short l = f2bf(x - bf2f(h));
      size_t o = (size_t)n * ND + (k ^ (((n >> 1) & 3) << 3));
      oh[o] = (short)h;
      ol[o] = (short)l;
    } else {
      _Float16* of = wf16 + (size_t)(y - 2) * ND * ND;
      of[(size_t)n * ND + (k ^ ((n & 7) << 3))] = (_Float16)x;
    }
  }
}

// ---------------- split-bf16 GEMM: C^T = (A f32 x BT split-bf16), out (B,1024,2048) f32 -----
// FUSED Q+K: 2048 blocks; sel = wg>>10 picks {queries,wq,Qt} vs {keys,wk,Kt}.
// Double-buffered BK=32: issue-early staging (A global->reg, B gll->LDS), write-late A split.
__global__ __launch_bounds__(256) void gemm_split(
    const float* __restrict__ Aq, const float* __restrict__ Ak,
    const short* __restrict__ wsplit, float* __restrict__ Qt, float* __restrict__ Kt) {
  constexpr int K = 1024;
  // 64KB: buf b at b*16384 shorts; within buf: ah 0, al 4096, bh 8192, bl 12288
  __shared__ short smem[32768];
  int t = threadIdx.x;
  // bijective XCD swizzle over 2048 blocks; each XCD stays within one operand set
  int wg = (blockIdx.x & 7) * 256 + (blockIdx.x >> 3);
  int sel = wg >> 10;
  int wgl = wg & 1023;
  const float* A = sel ? Ak : Aq;
  const short* BhT = wsplit + (size_t)(sel ? 2 : 0) * ND * ND;
  const short* BlT = wsplit + (size_t)(sel ? 3 : 1) * ND * ND;
  float* Ct = sel ? Kt : Qt;
  int m0 = (wgl >> 3) << 7, n0 = (wgl & 7) << 7;
  int lane = t & 63;
  int wm = (t >> 7) & 1, wn = (t >> 6) & 1;
  int lrow = lane & 15, lk8 = (lane >> 4) << 3;

  // staging geometry (per thread): rows r0 (it=0) and r1=r0+64 (it=1), k-chunk c8
  int r0 = t >> 2, r1 = r0 + 64;
  int c8 = (t & 3) << 3;
  int wi0 = r0 * 32 + (c8 ^ (((r0 >> 1) & 3) << 3));
  int wi1 = r1 * 32 + (c8 ^ (((r1 >> 1) & 3) << 3));
  int lo0 = (t & 192) * 8;         // wave-uniform LDS offset (shorts), it=0
  int lo1 = 2048 + (t & 192) * 8;  // it=1

  const float* pa0 = A + (size_t)(m0 + r0) * K + c8;
  const float* pa1 = A + (size_t)(m0 + r1) * K + c8;
  const short* pb0h = BhT + (size_t)(n0 + r0) * K + c8;
  const short* pb1h = BhT + (size_t)(n0 + r1) * K + c8;
  const short* pb0l = BlT + (size_t)(n0 + r0) * K + c8;
  const short* pb1l = BlT + (size_t)(n0 + r1) * K + c8;

  // loop-invariant fragment read offsets (shorts within a buffer)
  int iA[4], iB[4];
#pragma unroll
  for (int f = 0; f < 4; ++f) {
    int ra = wm * 64 + f * 16 + lrow;
    iA[f] = ra * 32 + (lk8 ^ (((ra >> 1) & 3) << 3));
    int rb = wn * 64 + f * 16 + lrow;
    iB[f] = rb * 32 + (lk8 ^ (((rb >> 1) & 3) << 3));
  }

  f32x4 acc[4][4] = {};

  // ---- prologue: stage k0=0 into buf0 ----
  float4 sx0 = *(const float4*)(pa0);
  float4 sy0 = *(const float4*)(pa0 + 4);
  float4 sx1 = *(const float4*)(pa1);
  float4 sy1 = *(const float4*)(pa1 + 4);
  gll16(pb0h, smem + 8192 + lo0);
  gll16(pb1h, smem + 8192 + lo1);
  gll16(pb0l, smem + 12288 + lo0);
  gll16(pb1l, smem + 12288 + lo1);
  asplit_write(sx0, sy0, smem, smem + 4096, wi0);
  asplit_write(sx1, sy1, smem, smem + 4096, wi1);
  __syncthreads();

  for (int k0 = 0; k0 < K; k0 += 32) {
    short* cb = smem + ((k0 >> 5) & 1) * 16384;
    short* nb = smem + ((((k0 >> 5) & 1) ^ 1) * 16384);
    bool more = (k0 + 32) < K;
    if (more) {
      // issue-early: next A tile -> regs, next B tile -> LDS (async)
      sx0 = *(const float4*)(pa0 + k0 + 32);
      sy0 = *(const float4*)(pa0 + k0 + 36);
      sx1 = *(const float4*)(pa1 + k0 + 32);
      sy1 = *(const float4*)(pa1 + k0 + 36);
      gll16(pb0h + k0 + 32, nb + 8192 + lo0);
      gll16(pb1h + k0 + 32, nb + 8192 + lo1);
      gll16(pb0l + k0 + 32, nb + 12288 + lo0);
      gll16(pb1l + k0 + 32, nb + 12288 + lo1);
    }
    // ---- compute from cb ----
    s16x8 afh[4], afl[4];
#pragma unroll
    for (int mf = 0; mf < 4; ++mf) {
      afh[mf] = *(const s16x8*)(cb + iA[mf]);
      afl[mf] = *(const s16x8*)(cb + 4096 + iA[mf]);
    }
#pragma unroll
    for (int nf = 0; nf < 4; ++nf) {
      s16x8 bfh = *(const s16x8*)(cb + 8192 + iB[nf]);
      s16x8 bfl = *(const s16x8*)(cb + 12288 + iB[nf]);
      // term-grouped: same-acc dependency distance = 4 MFMAs
#pragma unroll
      for (int mf = 0; mf < 4; ++mf)
        acc[mf][nf] = __builtin_amdgcn_mfma_f32_16x16x32_bf16(afh[mf], bfh, acc[mf][nf], 0, 0, 0);
#pragma unroll
      for (int mf = 0; mf < 4; ++mf)
        acc[mf][nf] = __builtin_amdgcn_mfma_f32_16x16x32_bf16(afh[mf], bfl, acc[mf][nf], 0, 0, 0);
#pragma unroll
      for (int mf = 0; mf < 4; ++mf)
        acc[mf][nf] = __builtin_amdgcn_mfma_f32_16x16x32_bf16(afl[mf], bfh, acc[mf][nf], 0, 0, 0);
    }
    if (more) {
      // write-late: split A into nb (compiler waits only the A loads, gll stays in flight)
      asplit_write(sx0, sy0, nb, nb + 4096, wi0);
      asplit_write(sx1, sy1, nb, nb + 4096, wi1);
    }
    __syncthreads();
  }

  // epilogue: C^T (B,1024,2048) f32, float4 stores along m
  int b = m0 >> 11;
  int mlbase = (m0 & 2047) + wm * 64 + (lane >> 4) * 4;
#pragma unroll
  for (int nf = 0; nf < 4; ++nf) {
    int n = n0 + wn * 64 + nf * 16 + lrow;
    float* rowp = Ct + ((size_t)(b * ND + n)) * NL + mlbase;
#pragma unroll
    for (int mf = 0; mf < 4; ++mf)
      *(float4*)(rowp + mf * 16) = *(float4*)&acc[mf][nf];
  }
}

// ---------------- f16 GEMM: A x BT(f16 pre-swizzled, gll), double-buffered ----------------
// AF32: A is f32 natural (issue-early reg stage, write-late cvt); else A f16 pre-swizzled (gll).
// OUTMODE 0: C^T (B,1024,2048) f16.
// OUTMODE 1: fused roll epilogue -> Xs (B*NL rows, swizzled f16).  Block owns 2 full heads.
// OUTMODE 2: C natural (16384x1024) f32.
template <int OUTMODE, bool AF32>
__global__ __launch_bounds__(256) void gemm_f16(
    const void* __restrict__ Av, const _Float16* __restrict__ BT,
    void* __restrict__ Cv, const float* __restrict__ topw, const int* __restrict__ topi) {
  constexpr int K = 1024;
  // 64KB: buf b at b*16384 halfs; within buf: sA 0, sB 8192. Reused as f32[128][128] in OUTMODE 1.
  __shared__ _Float16 smem[32768];
  __shared__ float wls[128][KTOP];
  __shared__ int tls[128][KTOP];
  int t = threadIdx.x;
  int wg = (blockIdx.x & 7) * 128 + (blockIdx.x >> 3);
  int m0 = (wg >> 3) << 7, n0 = (wg & 7) << 7;
  int lane = t & 63;
  int wm = (t >> 7) & 1, wn = (t >> 6) & 1;
  int lrow = lane & 15, lk = (lane >> 4) << 3;

  // staging geometry: per it (0..3): row = it*32 + (t>>3), k-chunk c8 = (t&7)*8
  int rs = t >> 3;
  int c8 = (t & 7) << 3;
  const _Float16* pB[4];
  const float* pAf[4];
  const _Float16* pAh[4];
  int wiA[4], lo[4];
#pragma unroll
  for (int it = 0; it < 4; ++it) {
    int r = it * 32 + rs;
    pB[it] = BT + (size_t)(n0 + r) * K + c8;
    lo[it] = it * 2048 + (t & 192) * 8;
    if (AF32) {
      pAf[it] = (const float*)Av + (size_t)(m0 + r) * K + c8;
      wiA[it] = r * 64 + (c8 ^ ((r & 7) << 3));
    } else {
      pAh[it] = (const _Float16*)Av + (size_t)(m0 + r) * K + c8;
    }
  }

  f32x4 acc[4][4] = {};
  float4 ax[4], ay[4];

  // prologue: stage k0=0 into buf0
#pragma unroll
  for (int it = 0; it < 4; ++it) {
    gll16(pB[it], smem + 8192 + lo[it]);
    if (!AF32) {
      gll16(pAh[it], smem + lo[it]);
    } else {
      ax[it] = *(const float4*)(pAf[it]);
      ay[it] = *(const float4*)(pAf[it] + 4);
    }
  }
  if (AF32) {
#pragma unroll
    for (int it = 0; it < 4; ++it) {
      f16x8 o;
      o[0] = (_Float16)ax[it].x; o[1] = (_Float16)ax[it].y;
      o[2] = (_Float16)ax[it].z; o[3] = (_Float16)ax[it].w;
      o[4] = (_Float16)ay[it].x; o[5] = (_Float16)ay[it].y;
      o[6] = (_Float16)ay[it].z; o[7] = (_Float16)ay[it].w;
      *(f16x8*)(smem + wiA[it]) = o;
    }
  }
  __syncthreads();

  for (int k0 = 0; k0 < K; k0 += 64) {
    _Float16* cb = smem + ((k0 >> 6) & 1) * 16384;
    _Float16* nb = smem + ((((k0 >> 6) & 1) ^ 1) * 16384);
    bool more = (k0 + 64) < K;
    if (more) {
#pragma unroll
      for (int it = 0; it < 4; ++it) {
        gll16(pB[it] + k0 + 64, nb + 8192 + lo[it]);
        if (!AF32) {
          gll16(pAh[it] + k0 + 64, nb + lo[it]);
        } else {
          ax[it] = *(const float4*)(pAf[it] + k0 + 64);
          ay[it] = *(const float4*)(pAf[it] + k0 + 68);
        }
      }
    }
    // compute from cb
#pragma unroll
    for (int kk = 0; kk < 64; kk += 32) {
      f16x8 af[4];
#pragma unroll
      for (int mf = 0; mf < 4; ++mf) {
        int row = wm * 64 + mf * 16 + lrow;
        af[mf] = *(const f16x8*)(cb + row * 64 + ((kk + lk) ^ ((row & 7) << 3)));
      }
#pragma unroll
      for (int nf = 0; nf < 4; ++nf) {
        int row = wn * 64 + nf * 16 + lrow;
        f16x8 bf = *(const f16x8*)(cb + 8192 + row * 64 + ((kk + lk) ^ ((row & 7) << 3)));
#pragma unroll
        for (int mf = 0; mf < 4; ++mf)
          acc[mf][nf] = __builtin_amdgcn_mfma_f32_16x16x32_f16(af[mf], bf, acc[mf][nf], 0, 0, 0);
      }
    }
    if (more && AF32) {
#pragma unroll
      for (int it = 0; it < 4; ++it) {
        f16x8 o;
        o[0] = (_Float16)ax[it].x; o[1] = (_Float16)ax[it].y;
        o[2] = (_Float16)ax[it].z; o[3] = (_Float16)ax[it].w;
        o[4] = (_Float16)ay[it].x; o[5] = (_Float16)ay[it].y;
        o[6] = (_Float16)ay[it].z; o[7] = (_Float16)ay[it].w;
        *(f16x8*)(nb + wiA[it]) = o;
      }
    }
    __syncthreads();
  }

  if (OUTMODE == 0) {
    _Float16* C = (_Float16*)Cv;
    int b = m0 >> 11;
    int ml = (m0 & 2047) + wm * 64 + (lane >> 4) * 4;
#pragma unroll
    for (int nf = 0; nf < 4; ++nf) {
      int n = n0 + wn * 64 + nf * 16 + lrow;
      _Float16* row = C + ((size_t)(b * ND + n)) * NL + ml;
#pragma unroll
      for (int mf = 0; mf < 4; ++mf) {
        f16x4 v;
        v[0] = (_Float16)acc[mf][nf][0];
        v[1] = (_Float16)acc[mf][nf][1];
        v[2] = (_Float16)acc[mf][nf][2];
        v[3] = (_Float16)acc[mf][nf][3];
        *(f16x4*)(row + mf * 16) = v;
      }
    }
  } else if (OUTMODE == 1) {
    // --- fused roll (mod-64 over Dh) + weight + scramble, from f32 acc ---
    float* ct = (float*)smem;  // 64KB (last __syncthreads of main loop protects reuse)
#pragma unroll
    for (int nf = 0; nf < 4; ++nf) {
      int nl = wn * 64 + nf * 16 + lrow;
#pragma unroll
      for (int mf = 0; mf < 4; ++mf) {
        int ml = wm * 64 + (lane >> 4) * 4 + mf * 16;
        int cc = (((ml >> 2) ^ (nl & 7)) << 2);
        *(float4*)(ct + nl * 128 + cc) = *(float4*)&acc[mf][nf];
      }
    }
    int b = m0 >> 11;
    int h0 = n0 >> 6;  // first head of the block (even)
    for (int e = t; e < 128 * KTOP; e += 256) {
      int nl = e / KTOP, i = e - nl * KTOP;  // nl = h_loc*64 + d
      size_t rix = ((size_t)(b * 16 + h0 + (nl >> 6))) * 64 + (nl & 63);
      wls[nl][i] = topw[rix * KTOP + i];
      tls[nl][i] = topi[rix * KTOP + i] & 63;
    }
    __syncthreads();

    int hi = (m0 >> 10) & 1;
    int cbase = (m0 & 2047) & 1023;  // D-col base (block spans 128 cols, hi fixed)
    _Float16* O = (_Float16*)Cv;
#pragma unroll
    for (int it2 = 0; it2 < 16; ++it2) {
      int o = it2 * 1024 + t * 4;
      int lr = o >> 7;    // local row = d*2 + h_loc
      int c4 = o & 127;   // m_local, multiple of 4
      int d = lr >> 1, hl = lr & 1;
      int wrow = hl * 64 + d;
      float4 s = {0.f, 0.f, 0.f, 0.f};
#pragma unroll
      for (int i = 0; i < KTOP; ++i) {
        int sr = hl * 64 + ((d - tls[wrow][i]) & 63);
        float w = wls[wrow][i];
        int scc = (((c4 >> 2) ^ (sr & 7)) << 2);
        float4 v = *(const float4*)(ct + sr * 128 + scc);
        s.x += w * v.x; s.y += w * v.y; s.z += w * v.z; s.w += w * v.w;
      }
      int rowp = d * 32 + (h0 + hl) * 2 + hi;
      int cg = cbase + c4;
      int cs = cg ^ ((rowp & 7) << 3);  // swizzle for O-GEMM's gll consumer
      f16x4 v4;
      v4[0] = (_Float16)s.x; v4[1] = (_Float16)s.y;
      v4[2] = (_Float16)s.z; v4[3] = (_Float16)s.w;
      *(f16x4*)(O + ((size_t)(b * NL + rowp)) * ND + cs) = v4;
    }
  } else {
    float* C = (float*)Cv;
#pragma unroll
    for (int mf = 0; mf < 4; ++mf)
#pragma unroll
      for (int nf = 0; nf < 4; ++nf) {
        int row = m0 + wm * 64 + mf * 16 + (lane >> 4) * 4;
        int col = n0 + wn * 64 + nf * 16 + lrow;
#pragma unroll
        for (int r = 0; r < 4; ++r)
          C[(size_t)(row + r) * ND + col] = acc[mf][nf][r];
      }
  }
}

// =================== FFT correlation + top-7 + softmax (register Stockham) ===================
__device__ __forceinline__ int SW(int i) { return i ^ ((i >> 4) & 7); }

__device__ __forceinline__ float2 cadd2(float2 a, float2 b) { return make_float2(a.x + b.x, a.y + b.y); }
__device__ __forceinline__ float2 csub2(float2 a, float2 b) { return make_float2(a.x - b.x, a.y - b.y); }
__device__ __forceinline__ float2 cmul2(float2 a, float2 b) {
  return make_float2(a.x * b.x - a.y * b.y, a.x * b.y + a.y * b.x);
}
__device__ __forceinline__ float2 cjs2(float2 a, float s) { return make_float2(-s * a.y, s * a.x); }
// e^{i*2*pi*rev} via HW trig (input in revolutions, |rev| < 1)
__device__ __forceinline__ float2 wtw(float rev) {
  return make_float2(__builtin_amdgcn_cosf(rev), __builtin_amdgcn_sinf(rev));
}

__device__ __forceinline__ void dft4(float2& b0, float2& b1, float2& b2, float2& b3, float s) {
  float2 t0 = cadd2(b0, b2), t1 = csub2(b0, b2);
  float2 t2 = cadd2(b1, b3), t3 = cjs2(csub2(b1, b3), s);
  b0 = cadd2(t0, t2);
  b1 = cadd2(t1, t3);
  b2 = csub2(t0, t2);
  b3 = csub2(t1, t3);
}

__device__ __forceinline__ void dft8(float2 a[8], float s) {
  float2 e0 = a[0], e1 = a[2], e2 = a[4], e3 = a[6];
  float2 o0 = a[1], o1 = a[3], o2 = a[5], o3 = a[7];
  dft4(e0, e1, e2, e3, s);
  dft4(o0, o1, o2, o3, s);
  const float c = 0.70710678118654752f;
  float2 w1 = make_float2(c, s * c);
  float2 w3 = make_float2(-c, s * c);
  o1 = cmul2(o1, w1);
  o2 = cjs2(o2, s);
  o3 = cmul2(o3, w3);
  a[0] = cadd2(e0, o0);
  a[4] = csub2(e0, o0);
  a[1] = cadd2(e1, o1);
  a[5] = csub2(e1, o1);
  a[2] = cadd2(e2, o2);
  a[6] = csub2(e2, o2);
  a[3] = cadd2(e3, o3);
  a[7] = csub2(e3, o3);
}

template <int LS>
__device__ __forceinline__ void pass8(const float2* __restrict__ in, float2* __restrict__ out,
                                      float s, int t) {
  float2 a[8];
  const float2* ip = in + (t ^ ((t >> 4) & 7));  // SW(t+256r) = SW(t)+256r (256r in bits>=8)
#pragma unroll
  for (int r = 0; r < 8; ++r) a[r] = ip[256 * r];
  int k = t & (LS - 1);
  if (LS > 1) {
    float kf = s * (1.0f / (LS * 8)) * (float)k;
    float2 w1 = wtw(kf);
    float2 w4 = wtw(4.0f * kf);
    float2 w2 = cmul2(w1, w1);
    float2 w3 = cmul2(w2, w1);
    float2 w5 = cmul2(w4, w1);
    float2 w6 = cmul2(w4, w2);
    float2 w7 = cmul2(w4, w3);
    a[1] = cmul2(a[1], w1);
    a[2] = cmul2(a[2], w2);
    a[3] = cmul2(a[3], w3);
    a[4] = cmul2(a[4], w4);
    a[5] = cmul2(a[5], w5);
    a[6] = cmul2(a[6], w6);
    a[7] = cmul2(a[7], w7);
  }
  dft8(a, s);
  int ob = (t / LS) * (LS * 8) + k;
#pragma unroll
  for (int r = 0; r < 8; ++r) out[SW(ob + LS * r)] = a[r];
}

__global__ __launch_bounds__(256) void fft_topk_kernel(
    const float* __restrict__ Qt, const float* __restrict__ Kt,
    float* __restrict__ topw, int* __restrict__ topi) {
  // LDS exactly 32KB -> 5 blocks/CU. cwv/cwt alias into X (X is dead by then).
  __shared__ float2 X[2048];
  __shared__ float2 Y[2048];
  float* cwv = (float*)X;         // 32 floats
  int* cwt = ((int*)X) + 32;      // 32 ints (256B total, within X)

  int t = threadIdx.x;
  size_t rix = blockIdx.x;
  const float* q = Qt + rix * NL;
  const float* k = Kt + rix * NL;

  // load packed z = Q + i*K. SW(i0+j) = SW(i0) ^ j for j<4 (XOR, not add!)
#pragma unroll
  for (int it = 0; it < 2; ++it) {
    int i0 = 4 * t + 1024 * it;
    float4 vq = *(const float4*)(q + i0);
    float4 vk = *(const float4*)(k + i0);
    int swb = SW(i0);
    X[swb ^ 0] = make_float2(vq.x, vk.x);
    X[swb ^ 1] = make_float2(vq.y, vk.y);
    X[swb ^ 2] = make_float2(vq.z, vk.z);
    X[swb ^ 3] = make_float2(vq.w, vk.w);
  }
  __syncthreads();

  // forward FFT (sign = -1): radix 8,8,8,4
  pass8<1>(X, Y, -1.0f, t);
  __syncthreads();
  pass8<8>(Y, X, -1.0f, t);
  __syncthreads();
  pass8<64>(X, Y, -1.0f, t);
  __syncthreads();

  // forward dft4 pass (Y -> X), keeping own outputs in fz[8] (zf re-reads avoided)
  float2 fz[8];
#pragma unroll
  for (int h = 0; h < 2; ++h) {
    int b = t + 256 * h;
    float2 a[4];
    const float2* yp = Y + SW(b);  // SW(b+512r)=SW(b)+512r (512r in bits>=9)
#pragma unroll
    for (int r = 0; r < 4; ++r) a[r] = yp[512 * r];
    float2 w = wtw(-(1.0f / 2048.0f) * (float)b);
    float2 w2 = cmul2(w, w);
    a[1] = cmul2(a[1], w);
    a[2] = cmul2(a[2], w2);
    a[3] = cmul2(a[3], cmul2(w2, w));
    dft4(a[0], a[1], a[2], a[3], -1.0f);
    float2* xp = X + SW(b);
#pragma unroll
    for (int r = 0; r < 4; ++r) {
      xp[512 * r] = a[r];
      fz[h + 2 * r] = a[r];
    }
  }
  __syncthreads();

  // FUSED: spectrum untangle (S = FQ*conj(FK) / 2048) + first inverse radix-8 pass -> Y.
  {
    float2 a[8];
#pragma unroll
    for (int r = 0; r < 8; ++r) {
      int f = t + 256 * r;
      int nf = (2048 - f) & 2047;
      float2 zf = fz[r];
      float2 zn = X[SW(nf)];
      float aa = zf.x, b2 = zf.y, c = zn.x, d = zn.y;
      float p = 0.5f * (aa + c), qq = 0.5f * (b2 - d);
      float r2 = 0.5f * (b2 + d), s2 = -0.5f * (aa - c);
      a[r] = make_float2((p * r2 + qq * s2) * (1.0f / 2048.0f),
                         (qq * r2 - p * s2) * (1.0f / 2048.0f));
    }
    dft8(a, 1.0f);  // LS=1: no twiddles
    int ob = t * 8;
#pragma unroll
    for (int r = 0; r < 8; ++r) Y[SW(ob + r)] = a[r];
  }
  __syncthreads();

  // remaining inverse passes: 8, 64, then final radix-4 kept in registers (reads Y)
  pass8<8>(Y, X, 1.0f, t);
  __syncthreads();
  pass8<64>(X, Y, 1.0f, t);
  __syncthreads();

  float lv[8];
  int lt[8];
#pragma unroll
  for (int h = 0; h < 2; ++h) {
    int b = t + 256 * h;
    float2 a[4];
    const float2* yp = Y + SW(b);
#pragma unroll
    for (int r = 0; r < 4; ++r) a[r] = yp[512 * r];
    float2 w = wtw((1.0f / 2048.0f) * (float)b);
    float2 w2 = cmul2(w, w);
    a[1] = cmul2(a[1], w);
    a[2] = cmul2(a[2], w2);
    a[3] = cmul2(a[3], cmul2(w2, w));
    dft4(a[0], a[1], a[2], a[3], 1.0f);
#pragma unroll
    for (int r = 0; r < 4; ++r) {
      lv[h * 4 + r] = a[r].x;
      lt[h * 4 + r] = b + 512 * r;
    }
  }

  // ---- top-7, barrier-light: wave-local 7 passes (no barriers), 1 barrier, wave-0 merge ----
  // X is dead now; cwv/cwt alias into it (the __syncthreads below orders the reuse).
  int lane = t & 63, wave = t >> 6;
  float bv = lv[0];
  int bt = lt[0];
#pragma unroll
  for (int j = 1; j < 8; ++j)
    if (lv[j] > bv) { bv = lv[j]; bt = lt[j]; }

  float myv = 0.f;
  int myt = 0;
#pragma unroll
  for (int pass = 0; pass < KTOP; ++pass) {
    float rv = bv;
    int rt = bt;
#pragma unroll
    for (int m = 1; m < 64; m <<= 1) {
      float ov = __shfl_xor(rv, m, 64);
      int ot = __shfl_xor(rt, m, 64);
      if (ov > rv) { rv = ov; rt = ot; }
    }
    if (lane == pass) { myv = rv; myt = rt; }  // static capture (lane==pass)
    if (bt == rt) {  // owner lane: invalidate + rescan (wave-local, position-unique)
#pragma unroll
      for (int j = 0; j < 8; ++j)
        if (lt[j] == rt) lv[j] = -3.0e38f;
      bv = lv[0];
      bt = lt[0];
#pragma unroll
      for (int j = 1; j < 8; ++j)
        if (lv[j] > bv) { bv = lv[j]; bt = lt[j]; }
    }
  }
  __syncthreads();  // all waves done reading X/Y before cwv/cwt overwrite X
  if (lane < KTOP) {
    cwv[wave * 8 + lane] = myv;
    cwt[wave * 8 + lane] = myt;
  }
  __syncthreads();

  if (wave == 0) {
    float mv = -3.0e38f;
    int mt = 0x7FFFFFFF;
    if (lane < 32 && (lane & 7) < KTOP) {
      mv = cwv[lane];
      mt = cwt[lane];
    }
    float sv = 0.f;
    int st = 0;
#pragma unroll
    for (int pass = 0; pass < KTOP; ++pass) {
      float rv = mv;
      int rt = mt;
#pragma unroll
      for (int m = 1; m < 64; m <<= 1) {
        float ov = __shfl_xor(rv, m, 64);
        int ot = __shfl_xor(rt, m, 64);
        if (ov > rv) { rv = ov; rt = ot; }
      }
      if (lane == pass) { sv = rv; st = rt; }
      if (mt == rt) mv = -3.0e38f;  // invalidate own candidate (tau unique)
    }
    // softmax over the 7 selected (lanes 0..6 hold sv/st)
    float m0v = __shfl(sv, 0, 64);
    float e = (lane < KTOP) ? expf(sv - m0v) : 0.0f;
    float ssum = e;
#pragma unroll
    for (int m = 1; m < 64; m <<= 1) ssum += __shfl_xor(ssum, m, 64);
    if (lane < KTOP) {
      topw[rix * KTOP + lane] = e / ssum;
      topi[rix * KTOP + lane] = st;
    }
  }
}

// ------------------------------------- launcher ---------------------------------------------
extern "C" void kernel_launch(void* const* d_in, const int* in_sizes, int n_in,
                              void* d_out, int out_size, void* d_ws, size_t ws_size,
                              hipStream_t stream) {
  (void)in_sizes; (void)n_in; (void)out_size; (void)ws_size;
  const float* queries = (const float*)d_in[0];
  const float* keys    = (const float*)d_in[1];
  const float* values  = (const float*)d_in[2];
  const float* wq = (const float*)d_in[3];
  const float* wk = (const float*)d_in[4];
  const float* wv = (const float*)d_in[5];
  const float* wo = (const float*)d_in[6];
  float* outp = (float*)d_out;

  const size_t MB = 1024 * 1024;
  char* ws = (char*)d_ws;
  short*    wsplit = (short*)ws;                  // wq/wk bf16 hi+lo: 8MB
  _Float16* wf16   = (_Float16*)(ws + 8 * MB);    // wv,wo f16: 4MB
  float*    Qt     = (float*)(ws + 12 * MB);      // (8,1024,2048) f32 = 64MB
  float*    Kt     = (float*)(ws + 76 * MB);      // 64MB; later Xs (f16)
  float*    topw   = (float*)(ws + 140 * MB);
  int*      topi   = (int*)(ws + 140 * MB + (size_t)8192 * KTOP * 4);

  _Float16* wv16 = wf16 + (size_t)0 * ND * ND;
  _Float16* wo16 = wf16 + (size_t)1 * ND * ND;

  _Float16* Xs = (_Float16*)Kt;  // reuse after fft

  wprep_kernel<<<dim3(1024, 4), 256, 0, stream>>>(wq, wk, wv, wo, wsplit, wf16);

  // fused Q+K projections (2048 blocks; sel by wg>>10)
  gemm_split<<<2048, 256, 0, stream>>>(queries, keys, wsplit, Qt, Kt);

  fft_topk_kernel<<<8192, 256, 0, stream>>>(Qt, Kt, topw, topi);

  // V projection + fused roll + scramble -> Xs (Kt dead after fft)
  gemm_f16<1, true><<<1024, 256, 0, stream>>>(values, wv16, Xs, topw, topi);

  gemm_f16<2, false><<<1024, 256, 0, stream>>>(Xs, wo16, outp, nullptr, nullptr);
}